// Round 5
// baseline (748.267 us; speedup 1.0000x reference)
//
#include <hip/hip_runtime.h>
#include <math.h>

#define KNOTS 1024
#define LNE 1e-5f
#define R0F 0.5f
#define RMAXF 6.0f
#define PAD 96

__device__ __forceinline__ float hermite_(float v0, float m0, float v1, float m1, float t){
  float A = v1 - v0;
  return v0 + t*(m0 + t*((3.f*A - 2.f*m0 - m1) + t*(m0 + m1 - 2.f*A)));
}

__device__ __forceinline__ float wsum64(float v){
#pragma unroll
  for(int m=32;m>=1;m>>=1) v += __shfl_xor(v, m, 64);
  return v;
}

__global__ __launch_bounds__(256) void k_zero(int* cnt, float* sumExp, int N){
  int i = blockIdx.x*256 + threadIdx.x;
  if(i < N) cnt[i] = 0;
  if(i == 0) sumExp[0] = 0.f;
}

__global__ __launch_bounds__(256) void k_weights(
    const float* ln1_g, const float* ln1_b, const float* W1, const float* b1,
    const float* ln2_g, const float* ln2_b, const float* W2, const float* b2,
    const float* ln3_g, const float* ln3_b, const float* W3, const float* b3,
    const float* resnet_p,
    float* W1gA, float* W1gB, float* W1gBot, float* W3gTop, float* W3gBot,
    float* colsum1, float* c1, float* colsum3, float* c3, float* W2g,
    float* cs1w3, float* c1w3, float* BW3, float* misc){
  int tid = threadIdx.x;
  for(int idx=tid; idx<4096; idx+=256){
    int k = idx>>6;
    W1gA[idx]   = ln1_g[k]*W1[idx];
    W1gB[idx]   = ln1_g[64+k]*W1[4096+idx];
    W3gTop[idx] = ln3_g[k]*W3[idx];
    W3gBot[idx] = ln3_g[64+k]*W3[4096+idx];
  }
  for(int idx=tid; idx<512; idx+=256) W1gBot[idx] = ln1_g[128+(idx>>6)]*W1[8192+idx];
  if(tid<128) W2g[tid] = ln2_g[tid]*W2[tid];
  if(tid<64){
    float cs=0.f, cc=0.f;
    for(int k=0;k<136;k++){ float wv = W1[k*64+tid]; cs += ln1_g[k]*wv; cc += ln1_b[k]*wv; }
    colsum1[tid] = cs; c1[tid] = cc + b1[tid];
    float cs3=0.f, cc3=0.f;
    for(int k=0;k<128;k++){ float wv = W3[k*64+tid]; cs3 += ln3_g[k]*wv; cc3 += ln3_b[k]*wv; }
    colsum3[tid] = cs3; c3[tid] = cc3 + b3[tid];
  }
  if(tid==0){
    float cs2=0.f, cc2=0.f;
    for(int k=0;k<128;k++){ cs2 += ln2_g[k]*W2[k]; cc2 += ln2_b[k]*W2[k]; }
    misc[0]=cs2; misc[1]=cc2 + b2[0];
    float p = resnet_p[0];
    float uc = 1.f/(1.f+expf(-p));
    float co = rsqrtf(uc*uc+1.f);
    misc[2] = uc*co*(1.f + co + co*co);   // 3-recycle collapse factor
  }
  __syncthreads();
  if(tid<64){
    float a=0.f, b=0.f;
    for(int k=0;k<64;k++){ float wv = W3gTop[k*64+tid]; a += colsum1[k]*wv; b += c1[k]*wv; }
    cs1w3[tid]=a; c1w3[tid]=b;
  }
  for(int idx=tid; idx<512; idx+=256){
    int kk = idx>>6, j = idx&63;
    float a=0.f;
    for(int k=0;k<64;k++) a += W1gBot[kk*64+k]*W3gTop[k*64+j];
    BW3[idx]=a;
  }
  if(tid==0){
    float a=0.f,b=0.f;
    for(int k=0;k<64;k++){ a += colsum1[k]*W2g[k]; b += c1[k]*W2g[k]; }
    misc[3]=a; misc[4]=b;
    float a5=0.f, a6=0.f;
    for(int k=0;k<64;k++){ a5 += colsum1[k]; a6 += c1[k]; }
    misc[5]=a5; misc[6]=a6;   // sum(colsum1), sum(c1)
    float gg=0.f, gc=0.f, ccs=0.f;
    for(int k=0;k<64;k++){ float g=colsum1[k], c=c1[k]; gg+=g*g; gc+=g*c; ccs+=c*c; }
    misc[16]=gg; misc[17]=gc; misc[18]=ccs;  // sum g^2, sum g*c1, sum c1^2
  }
  if(tid<8){
    float a=0.f;
    for(int k=0;k<64;k++) a += W1gBot[tid*64+k]*W2g[k];
    misc[8+tid]=a;
  }
}

__device__ __forceinline__ void eval_all(
    float r, const float* W1gBot, const float* BW3, const float* bw2,
    const float* F1, const float* F2, float* uL, int lane, float* rbfO,
    float& T1, float& T13, float& T12, float& gate, float& sr, float& sq){
  float rbf[8];
  float inv_r = 1.f/r;
  float x = r*(1.f/6.f);
  float x2 = x*x;
  float x6 = x2*x2*x2;
  float th = tanhf(1.f - x6);
  float cut = th*th*th;
  float pref = 0.57735026919f*inv_r*cut;   // sqrt(2/6)
  sr=0.f; sq=0.f;
#pragma unroll
  for(int n=0;n<8;n++){
    float b = pref*sinf((float)(n+1)*0.52359877559f*r);   // pi/6
    rbf[n]=b; rbfO[n]=b; sr+=b; sq+=b*b;
  }
  float t1=0.f,t3=0.f,t2=0.f;
#pragma unroll
  for(int k=0;k<8;k++){
    t1 += rbf[k]*W1gBot[k*64+lane];
    t3 += rbf[k]*BW3[k*64+lane];
    t2 += rbf[k]*bw2[k];
  }
  T1=t1; T13=t3; T12=t2;
  float a0=0.f,a1=0.f,g0=0.f,g1=0.f;
#pragma unroll
  for(int k=0;k<8;k++){
    const float* row = F1 + k*256;
    float rb = rbf[k];
    a0 += rb*row[lane];      a1 += rb*row[64+lane];
    g0 += rb*row[128+lane];  g1 += rb*row[192+lane];
  }
  uL[lane]    = (a0/(1.f+expf(-a0)))*g0;
  uL[64+lane] = (a1/(1.f+expf(-a1)))*g1;
  float accv = 0.f;
  for(int i2=0;i2<128;i2++) accv += uL[i2]*F2[i2*64+lane];
  gate = 1.f/(1.f+expf(-accv));
}

// tabS[knot][16]: {sr,dsr, sq,dsq, t12,dt12, sT1,dsT1, T11,dT11, T1g,dT1g, T1c1,dT1c1, 0,0}
// tabRbf[knot][16]: {rbf_k, drbf_k} x8
// tab2[knot*64+lane] float4: {T13, dT13, G, dG}
__global__ __launch_bounds__(256) void k_tables(
    const float* W1gBot, const float* BW3, const float* misc,
    const float* F1, const float* F2, const float* colsum1, const float* c1,
    float* tab2, float* tabS, float* tabRbf){
  __shared__ __align__(16) float u[4][128];
  int lane = threadIdx.x&63, w = threadIdx.x>>6;
  int knot = blockIdx.x*4 + w;
  if(knot > KNOTS) return;
  const float H = (RMAXF-R0F)/KNOTS;
  float r = R0F + knot*H;
  const float dh = 1e-3f;
  const float* bw2 = misc+8;
  float rbc[8], rbp[8], rbm[8];
  float T1c,T13c,T12c,Gc,SRc,SQc, T1p,T13p,T12p,Gp,SRp,SQp, T1m,T13m,T12m,Gm,SRm,SQm;
  eval_all(r,    W1gBot,BW3,bw2,F1,F2,u[w],lane, rbc, T1c,T13c,T12c,Gc,SRc,SQc);
  eval_all(r+dh, W1gBot,BW3,bw2,F1,F2,u[w],lane, rbp, T1p,T13p,T12p,Gp,SRp,SQp);
  eval_all(r-dh, W1gBot,BW3,bw2,F1,F2,u[w],lane, rbm, T1m,T13m,T12m,Gm,SRm,SQm);
  float sc = H/(2.f*dh);
  float cg = colsum1[lane], cl = c1[lane];
  float sT1c = wsum64(T1c), sT1p = wsum64(T1p), sT1m = wsum64(T1m);
  float T11c = wsum64(T1c*T1c), T11p = wsum64(T1p*T1p), T11m = wsum64(T1m*T1m);
  float T1gc = wsum64(T1c*cg), T1gp = wsum64(T1p*cg), T1gm = wsum64(T1m*cg);
  float T1cc = wsum64(T1c*cl), T1cp = wsum64(T1p*cl), T1cm = wsum64(T1m*cl);
  ((float4*)tab2)[knot*64+lane] = make_float4(T13c,(T13p-T13m)*sc, Gc,(Gp-Gm)*sc);
  if(lane==0){
    float* d = tabS + knot*16;
    d[0]=SRc;  d[1]=(SRp-SRm)*sc;   d[2]=SQc;  d[3]=(SQp-SQm)*sc;
    d[4]=T12c; d[5]=(T12p-T12m)*sc; d[6]=sT1c; d[7]=(sT1p-sT1m)*sc;
    d[8]=T11c; d[9]=(T11p-T11m)*sc; d[10]=T1gc; d[11]=(T1gp-T1gm)*sc;
    d[12]=T1cc; d[13]=(T1cp-T1cm)*sc; d[14]=0.f; d[15]=0.f;
    float* rb = tabRbf + knot*16;
#pragma unroll
    for(int k=0;k<8;k++){ rb[2*k]=rbc[k]; rb[2*k+1]=(rbp[k]-rbm[k])*sc; }
  }
}

// nodeC[v][16]: {nS, nSQ, nT, PW2, SPP, SPg, SPc1, sumP, PB0..7}
// nodeN[v][16]: {nS, nSQ, sumQ, QW2, SQQ, SQg, SQc1, 0, QB0..7}
__global__ __launch_bounds__(256) void k_node(
    const float* attrs, const float* W1gA, const float* W1gB, const float* W3gTop,
    const float* W2g, const float* W1gBot, const float* colsum1, const float* c1,
    float* P, float* Q, float* QW3, float* PW3R,
    float* nodeC, float* nodeN, int N){
  __shared__ __align__(16) float sb[4][192];
  int v = (blockIdx.x*256+threadIdx.x)>>6;
  int lane = threadIdx.x&63, w = (threadIdx.x>>6)&3;
  if(v>=N) return;
  const float* av = attrs + (size_t)v*64;
  float al = av[lane];
  sb[w][lane] = al;
  float s = wsum64(al), sqv = wsum64(al*al), t = wsum64(al*W2g[64+lane]);
  float p=0.f, q=0.f;
  const float4* avv = (const float4*)(&sb[w][0]);
#pragma unroll
  for(int kk=0;kk<16;kk++){
    float4 x = avv[kk];
    const float* wa = W1gA + kk*256 + lane;
    const float* wb = W1gB + kk*256 + lane;
    p += x.x*wa[0] + x.y*wa[64] + x.z*wa[128] + x.w*wa[192];
    q += x.x*wb[0] + x.y*wb[64] + x.z*wb[128] + x.w*wb[192];
  }
  P[v*64+lane]=p; Q[v*64+lane]=q;
  float sp = wsum64(p), sq2 = wsum64(q);
  float pw2 = wsum64(p*W2g[lane]), qw2 = wsum64(q*W2g[lane]);
  float cg = colsum1[lane], cl = c1[lane];
  float SPP = wsum64(p*p), SQQ = wsum64(q*q);
  float SPg = wsum64(p*cg), SQg = wsum64(q*cg);
  float SPc = wsum64(p*cl), SQc = wsum64(q*cl);
  float pbv[8], qbv[8];
#pragma unroll
  for(int k=0;k<8;k++){
    float wv = W1gBot[k*64+lane];
    pbv[k] = wsum64(p*wv);
    qbv[k] = wsum64(q*wv);
  }
  sb[w][64+lane]=p; sb[w][128+lane]=q;
  float ap=0.f, aq=0.f;
  const float4* pv = (const float4*)(&sb[w][64]);
  const float4* qv = (const float4*)(&sb[w][128]);
#pragma unroll
  for(int kk=0;kk<16;kk++){
    float4 xp = pv[kk], xq = qv[kk];
    const float* wc = W3gTop + kk*256 + lane;
    ap += xp.x*wc[0] + xp.y*wc[64] + xp.z*wc[128] + xp.w*wc[192];
    aq += xq.x*wc[0] + xq.y*wc[64] + xq.z*wc[128] + xq.w*wc[192];
  }
  PW3R[v*128 + 2*lane] = ap;
  QW3[v*64+lane] = aq;
  if(lane==0){
    float* nc = nodeC + v*16;
    nc[0]=s; nc[1]=sqv; nc[2]=t; nc[3]=pw2; nc[4]=SPP; nc[5]=SPg; nc[6]=SPc; nc[7]=sp;
#pragma unroll
    for(int k=0;k<8;k++) nc[8+k]=pbv[k];
    float* nn = nodeN + v*16;
    nn[0]=s; nn[1]=sqv; nn[2]=sq2; nn[3]=qw2; nn[4]=SQQ; nn[5]=SQg; nn[6]=SQc; nn[7]=0.f;
#pragma unroll
    for(int k=0;k<8;k++) nn[8+k]=qbv[k];
  }
}

__global__ __launch_bounds__(256) void k_bin(const int* ei, const float* elen,
                                             int* cnt, float4* binRec, int N, int E){
  int e = blockIdx.x*256+threadIdx.x;
  if(e<E){
    int c = ei[e]; c = min(max(c,0),N-1);
    int nb = ei[E+e]; nb = min(max(nb,0),N-1);
    float r = elen[e];
    int pos = atomicAdd(&cnt[c],1);
    if(pos < PAD)
      binRec[c*PAD+pos] = make_float4(__int_as_float(nb), r, __int_as_float(e), 0.f);
  }
}

// Two-phase pool. Phase 1: lane-per-edge scalar precompute into LDS.
// Phase 2: slim wave-per-node loop — Q gather, T1 from registers, one dot-reduce.
__global__ __launch_bounds__(256) void k_pool(
    const float4* binRec, const int* cnt,
    const float* P, const float* Q,
    const float* nodeC, const float* nodeN, const float* W1gBot,
    const float* colsum1, const float* c1, const float* misc,
    const float* tabS, const float* tabRbf,
    float* pooled, float4* aux, float* sumExp, int N){
  __shared__ float scal[4][PAD][17];
  int w = threadIdx.x>>6, lane = threadIdx.x&63;
  int v = blockIdx.x*4 + w;
  int vv = min(v, N-1);
  int deg = (v<N) ? min(cnt[vv], PAD) : 0;
  const float invH = (float)KNOTS/(RMAXF-R0F);
  int base = vv*PAD;
  // ---- phase 1: per-edge scalars, lane-parallel
  {
    float cc0=nodeC[vv*16+0], cc1=nodeC[vv*16+1], cc3=nodeC[vv*16+3];
    float cc4=nodeC[vv*16+4], cc5=nodeC[vv*16+5], cc6=nodeC[vv*16+6], cc7=nodeC[vv*16+7];
    float pb[8];
#pragma unroll
    for(int k=0;k<8;k++) pb[k]=nodeC[vv*16+8+k];
    float csw2=misc[3], cw2=misc[4], sumCol=misc[5], sumC1=misc[6];
    float Sgg=misc[16], Sgc1=misc[17], Sc1c1=misc[18];
    for(int slot=lane; slot<deg; slot+=64){
      float4 rec = binRec[base+slot];
      int nb = __float_as_int(rec.x);
      float r = rec.y;
      float uu = (r-R0F)*invH;
      int ti = (int)uu; ti = min(max(ti,0),KNOTS-1);
      float tt = uu-(float)ti;
      const float4* sA4 = (const float4*)(tabS + ti*16);
      const float4* sB4 = (const float4*)(tabS + (ti+1)*16);
      float4 sA0=sA4[0], sA1=sA4[1], sA2=sA4[2], sA3=sA4[3];
      float4 sB0=sB4[0], sB1=sB4[1], sB2=sB4[2], sB3=sB4[3];
      const float4* rA4 = (const float4*)(tabRbf + ti*16);
      const float4* rB4 = (const float4*)(tabRbf + (ti+1)*16);
      float rbf[8];
      {
        float4 a0=rA4[0], a1=rA4[1], a2=rA4[2], a3=rA4[3];
        float4 b0=rB4[0], b1=rB4[1], b2=rB4[2], b3=rB4[3];
        rbf[0]=hermite_(a0.x,a0.y,b0.x,b0.y,tt); rbf[1]=hermite_(a0.z,a0.w,b0.z,b0.w,tt);
        rbf[2]=hermite_(a1.x,a1.y,b1.x,b1.y,tt); rbf[3]=hermite_(a1.z,a1.w,b1.z,b1.w,tt);
        rbf[4]=hermite_(a2.x,a2.y,b2.x,b2.y,tt); rbf[5]=hermite_(a2.z,a2.w,b2.z,b2.w,tt);
        rbf[6]=hermite_(a3.x,a3.y,b3.x,b3.y,tt); rbf[7]=hermite_(a3.z,a3.w,b3.z,b3.w,tt);
      }
      float srb = hermite_(sA0.x,sA0.y,sB0.x,sB0.y,tt);
      float sqb = hermite_(sA0.z,sA0.w,sB0.z,sB0.w,tt);
      float t1w2= hermite_(sA1.x,sA1.y,sB1.x,sB1.y,tt);
      float sT1 = hermite_(sA1.z,sA1.w,sB1.z,sB1.w,tt);
      float T11 = hermite_(sA2.x,sA2.y,sB2.x,sB2.y,tt);
      float T1g = hermite_(sA2.z,sA2.w,sB2.z,sB2.w,tt);
      float T1c1= hermite_(sA3.x,sA3.y,sB3.x,sB3.y,tt);
      const float4* nn4 = (const float4*)(nodeN + (size_t)nb*16);
      float4 nn0=nn4[0], nn1=nn4[1], nn2=nn4[2], nn3=nn4[3];
      float PT1 = rbf[0]*pb[0]+rbf[1]*pb[1]+rbf[2]*pb[2]+rbf[3]*pb[3]
                + rbf[4]*pb[4]+rbf[5]*pb[5]+rbf[6]*pb[6]+rbf[7]*pb[7];
      float QT1 = rbf[0]*nn2.x+rbf[1]*nn2.y+rbf[2]*nn2.z+rbf[3]*nn2.w
                + rbf[4]*nn3.x+rbf[5]*nn3.y+rbf[6]*nn3.z+rbf[7]*nn3.w;
      float m = (cc0 + nn0.x + srb)*(1.f/136.f);
      float var = (cc1 + nn0.y + sqb)*(1.f/136.f) - m*m;
      float rs = rsqrtf(var + LNE);
      float sumEf = rs*(cc7 + nn0.z + sT1 - m*sumCol) + sumC1;
      float sw = rs*(cc3 + nn0.w + t1w2 - m*csw2) + cw2;
      float SS0 = rs*rs*(cc4 + nn1.x + T11 + 2.f*(PT1+QT1)
                          - 2.f*m*(cc5 + nn1.y + T1g) + m*m*Sgg)
                + 2.f*rs*(cc6 + nn1.z + T1c1 - m*Sgc1) + Sc1c1;
      float* L = &scal[w][slot][0];
      L[0]=rs; L[1]=m; L[2]=sumEf; L[3]=sw; L[4]=SS0; L[5]=2.f*rs*rs;
#pragma unroll
      for(int k=0;k<8;k++) L[6+k]=rbf[k];
    }
  }
  __syncthreads();
  // ---- phase 2: wave-per-node, vector-minimal
  float acc = 0.f, accE = 0.f;
  if(v < N && deg > 0){
    float Pl = P[vv*64+lane];
    float colg1 = colsum1[lane], c1l = c1[lane];
    float w1b[8];
#pragma unroll
    for(int k=0;k<8;k++) w1b[k] = W1gBot[k*64+lane];
    float cc0=nodeC[vv*16+0], cc1=nodeC[vv*16+1], cc2=nodeC[vv*16+2];
    float cs2=misc[0], c2v=misc[1];
    const float inv128 = 1.f/128.f;
    int i1 = min(1, deg-1);
    float4 rA = binRec[base], rB = binRec[base+i1];
    float qA = Q[__float_as_int(rA.x)*64+lane];
    float qB = Q[__float_as_int(rB.x)*64+lane];
    for(int i=0; i<deg; i+=2){
      float4 recA = rA, recB = rB;
      float QlA = qA, QlB = qB;
      bool hasB = (i+1) < deg;
      int iB = min(i+1, deg-1);
      if(i+2 < deg){
        int p0 = i+2, p1 = min(i+3, deg-1);
        rA = binRec[base+p0]; rB = binRec[base+p1];
        qA = Q[__float_as_int(rA.x)*64+lane];
        qB = Q[__float_as_int(rB.x)*64+lane];
      }
      const float* LA = &scal[w][i][0];
      const float* LB = &scal[w][iB][0];
      float rsA=LA[0], mA=LA[1], seA=LA[2], swA=LA[3], S0A=LA[4], cdA=LA[5];
      float rsB=LB[0], mB=LB[1], seB=LB[2], swB=LB[3], S0B=LB[4], cdB=LB[5];
      float T1A = LA[6]*w1b[0]+LA[7]*w1b[1]+LA[8]*w1b[2]+LA[9]*w1b[3]
                + LA[10]*w1b[4]+LA[11]*w1b[5]+LA[12]*w1b[6]+LA[13]*w1b[7];
      float T1B = LB[6]*w1b[0]+LB[7]*w1b[1]+LB[8]*w1b[2]+LB[9]*w1b[3]
                + LB[10]*w1b[4]+LB[11]*w1b[5]+LB[12]*w1b[6]+LB[13]*w1b[7];
      float efA = rsA*(Pl + QlA + T1A - mA*colg1) + c1l;
      float efB = rsB*(Pl + QlB + T1B - mB*colg1) + c1l;
      float dA = Pl*QlA, dB = Pl*QlB;
#pragma unroll
      for(int msk=32; msk>=1; msk>>=1){
        dA += __shfl_xor(dA,msk,64);
        dB += __shfl_xor(dB,msk,64);
      }
      float r1A = S0A + cdA*dA;
      float m2A = (seA + cc0)*inv128;
      float var2A = (r1A + cc1)*inv128 - m2A*m2A;
      float rs2A = rsqrtf(var2A + LNE);
      float scoreA = rs2A*(swA + cc2 - m2A*cs2) + c2v;
      float eevA = __expf(scoreA);
      acc += eevA*efA; accE += eevA;
      if(lane==0) aux[__float_as_int(recA.z)] = make_float4(r1A, rsA, mA, seA);
      if(hasB){
        float r1B = S0B + cdB*dB;
        float m2B = (seB + cc0)*inv128;
        float var2B = (r1B + cc1)*inv128 - m2B*m2B;
        float rs2B = rsqrtf(var2B + LNE);
        float scoreB = rs2B*(swB + cc2 - m2B*cs2) + c2v;
        float eevB = __expf(scoreB);
        acc += eevB*efB; accE += eevB;
        if(lane==0) aux[__float_as_int(recB.z)] = make_float4(r1B, rsB, mB, seB);
      }
    }
  }
  if(v < N){
    pooled[vv*64+lane] = acc;
    if(lane==0 && accE != 0.f) atomicAdd(sumExp, accE);
  }
}

__global__ __launch_bounds__(256) void k_node2(
    const float* pooledRaw, const float* sumExp, const float* W3gBot, const float* nodeC,
    float* PW3R, float4* packF, int N){
  __shared__ __align__(16) float sb[4][64];
  int v = (blockIdx.x*256+threadIdx.x)>>6;
  int lane = threadIdx.x&63, w = (threadIdx.x>>6)&3;
  if(v>=N) return;
  float inv = 1.f/sumExp[0];
  float pl = pooledRaw[v*64+lane]*inv;
  float s = wsum64(pl), sq = wsum64(pl*pl);
  sb[w][lane] = pl;
  float acc = 0.f;
  const float4* pv = (const float4*)(&sb[w][0]);
#pragma unroll
  for(int kk=0;kk<16;kk++){
    float4 x = pv[kk];
    const float* wc = W3gBot + kk*256 + lane;
    acc += x.x*wc[0] + x.y*wc[64] + x.z*wc[128] + x.w*wc[192];
  }
  PW3R[v*128 + 2*lane + 1] = acc;   // R component
  if(lane==0){ packF[v] = make_float4(s, sq, nodeC[v*16+7], 0.f); }
}

#define FCHUNK 16
__global__ __launch_bounds__(256) void k_final(
    const int* ei, const float* elen, const float4* aux,
    const float* QW3, const float* PW3R, const float4* packF,
    const float* cs1w3, const float* c1w3, const float* colsum3, const float* c3,
    const float* misc, const float* tab2,
    float* out, int N, int E){
  int w = threadIdx.x>>6, lane = threadIdx.x&63;
  int st = (blockIdx.x*4 + w)*FCHUNK;
  if(st >= E) return;
  int ed = min(st+FCHUNK, E);
  float csw3 = cs1w3[lane], cw3 = c1w3[lane];
  float col3 = colsum3[lane], c3l = c3[lane];
  float SC = misc[2];
  const float invH = (float)KNOTS/(RMAXF-R0F);
  for(int i=st; i<ed; i+=2){
    int eA = i, eB = min(i+1, ed-1);
    int cA = ei[eA];   cA = min(max(cA,0),N-1);
    int nA = ei[E+eA]; nA = min(max(nA,0),N-1);
    int cB = ei[eB];   cB = min(max(cB,0),N-1);
    int nB = ei[E+eB]; nB = min(max(nB,0),N-1);
    float rrA = elen[eA], rrB = elen[eB];
    float4 xA = aux[eA], xB = aux[eB];
    float2 pwA = ((const float2*)PW3R)[cA*64+lane];
    float2 pwB = ((const float2*)PW3R)[cB*64+lane];
    float q3A = QW3[nA*64+lane];
    float q3B = QW3[nB*64+lane];
    float4 pfA = packF[cA], pfB = packF[cB];
    float uuA = (rrA - R0F)*invH;
    int tiA = (int)uuA; tiA = min(max(tiA,0),KNOTS-1);
    float ttA = uuA - (float)tiA;
    int tbA = tiA*64+lane;
    float uuB = (rrB - R0F)*invH;
    int tiB = (int)uuB; tiB = min(max(tiB,0),KNOTS-1);
    float ttB = uuB - (float)tiB;
    int tbB = tiB*64+lane;
    float4 t2aA = ((const float4*)tab2)[tbA], t2bA = ((const float4*)tab2)[tbA+64];
    float4 t2aB = ((const float4*)tab2)[tbB], t2bB = ((const float4*)tab2)[tbB+64];
    {
      float T13 = hermite_(t2aA.x,t2aA.y,t2bA.x,t2bA.y,ttA);
      float gate= hermite_(t2aA.z,t2aA.w,t2bA.z,t2bA.w,ttA);
      float r1 = xA.x, rs = xA.y, m = xA.z, sEf = xA.w;
      float efd = rs*(pwA.x + q3A + T13 - m*csw3) + cw3;
      float m3 = (sEf + pfA.x)*(1.f/128.f);
      float var3 = (r1 + pfA.y)*(1.f/128.f) - m3*m3;
      float rs3 = rsqrtf(var3 + LNE);
      float upd = rs3*(efd + pwA.y - m3*col3) + c3l;
      out[(size_t)eA*64 + lane] = SC*upd*gate;
    }
    {
      float T13 = hermite_(t2aB.x,t2aB.y,t2bB.x,t2bB.y,ttB);
      float gate= hermite_(t2aB.z,t2aB.w,t2bB.z,t2bB.w,ttB);
      float r1 = xB.x, rs = xB.y, m = xB.z, sEf = xB.w;
      float efd = rs*(pwB.x + q3B + T13 - m*csw3) + cw3;
      float m3 = (sEf + pfB.x)*(1.f/128.f);
      float var3 = (r1 + pfB.y)*(1.f/128.f) - m3*m3;
      float rs3 = rsqrtf(var3 + LNE);
      float upd = rs3*(efd + pwB.y - m3*col3) + c3l;
      out[(size_t)eB*64 + lane] = SC*upd*gate;
    }
  }
}

extern "C" void kernel_launch(void* const* d_in, const int* in_sizes, int n_in,
                              void* d_out, int out_size, void* d_ws, size_t ws_size,
                              hipStream_t stream){
  const int*   ei    = (const int*)  d_in[0];
  const float* elen  = (const float*)d_in[1];
  const float* attrs = (const float*)d_in[2];
  const float* ln1_g = (const float*)d_in[3];
  const float* ln1_b = (const float*)d_in[4];
  const float* W1    = (const float*)d_in[5];
  const float* b1    = (const float*)d_in[6];
  const float* ln2_g = (const float*)d_in[7];
  const float* ln2_b = (const float*)d_in[8];
  const float* W2    = (const float*)d_in[9];
  const float* b2    = (const float*)d_in[10];
  const float* ln3_g = (const float*)d_in[11];
  const float* ln3_b = (const float*)d_in[12];
  const float* W3    = (const float*)d_in[13];
  const float* b3    = (const float*)d_in[14];
  const float* F1    = (const float*)d_in[15];
  const float* F2    = (const float*)d_in[16];
  const float* resp  = (const float*)d_in[17];
  const int E = in_sizes[1];
  const int N = in_sizes[2]/64;
  float* ws = (float*)d_ws;
  size_t o = 0;
  auto A = [&](size_t n){ size_t rr = o; o += (n + 63) & ~(size_t)63; return rr; };
  float* P      = ws + A((size_t)N*64);
  float* Q      = ws + A((size_t)N*64);
  float* QW3    = ws + A((size_t)N*64);
  float* PW3R   = ws + A((size_t)N*128);
  float* pooled = ws + A((size_t)N*64);
  float* nodeC  = ws + A((size_t)N*16);
  float* nodeN  = ws + A((size_t)N*16);
  float4* packF = (float4*)(ws + A((size_t)N*4));
  float* W1gA   = ws + A(4096);
  float* W1gB   = ws + A(4096);
  float* W1gBot = ws + A(512);
  float* W3gTop = ws + A(4096);
  float* W3gBot = ws + A(4096);
  float* BW3    = ws + A(512);
  float* colsum1= ws + A(64);
  float* c1     = ws + A(64);
  float* cs1w3  = ws + A(64);
  float* c1w3   = ws + A(64);
  float* colsum3= ws + A(64);
  float* c3     = ws + A(64);
  float* W2g    = ws + A(128);
  float* misc   = ws + A(64);
  float* tab2   = ws + A((size_t)(KNOTS+1)*256);
  float* tabS   = ws + A((size_t)(KNOTS+1)*16);
  float* tabRbf = ws + A((size_t)(KNOTS+1)*16);
  float* sumExp = ws + A(64);
  int* cnt      = (int*)(ws + A((size_t)N));
  float4* binRec= (float4*)(ws + A((size_t)N*PAD*4));
  float4* aux   = (float4*)(ws + A((size_t)E*4));
  (void)ws_size; (void)out_size; (void)n_in;
  float* out = (float*)d_out;

  int nb4 = (N+3)/4;
  k_zero<<<(N+255)/256, 256, 0, stream>>>(cnt, sumExp, N);
  k_weights<<<1,256,0,stream>>>(ln1_g,ln1_b,W1,b1,ln2_g,ln2_b,W2,b2,ln3_g,ln3_b,W3,b3,resp,
      W1gA,W1gB,W1gBot,W3gTop,W3gBot,colsum1,c1,colsum3,c3,W2g,cs1w3,c1w3,BW3,misc);
  k_tables<<<(KNOTS+4)/4, 256, 0, stream>>>(W1gBot,BW3,misc,F1,F2,colsum1,c1,tab2,tabS,tabRbf);
  k_node<<<nb4,256,0,stream>>>(attrs,W1gA,W1gB,W3gTop,W2g,W1gBot,colsum1,c1,P,Q,QW3,PW3R,nodeC,nodeN,N);
  k_bin<<<(E+255)/256,256,0,stream>>>(ei,elen,cnt,binRec,N,E);
  k_pool<<<nb4,256,0,stream>>>(binRec,cnt,P,Q,nodeC,nodeN,W1gBot,colsum1,c1,misc,tabS,tabRbf,pooled,aux,sumExp,N);
  k_node2<<<nb4,256,0,stream>>>(pooled,sumExp,W3gBot,nodeC,PW3R,packF,N);
  {
    int chunks = (E + FCHUNK - 1)/FCHUNK;
    int blocks = (chunks + 3)/4;
    k_final<<<blocks,256,0,stream>>>(ei,elen,aux,QW3,PW3R,packF,cs1w3,c1w3,colsum3,c3,misc,tab2,out,N,E);
  }
}